// Round 3
// baseline (156.503 us; speedup 1.0000x reference)
//
#include <hip/hip_runtime.h>
#include <stdint.h>

#define B_ 4096
#define D_ 1024
#define TINV 10.0f
#define LOG2E 1.4426950408889634f
#define KE (TINV * LOG2E)
#define INV_BM1 (1.0f / 4095.0f)

typedef __bf16 bf16x8 __attribute__((ext_vector_type(8)));
typedef float f32x4 __attribute__((ext_vector_type(4)));

__device__ __forceinline__ unsigned short f2bf(float x) {
  uint32_t b = __float_as_uint(x);
  b += 0x7FFF + ((b >> 16) & 1);   // RNE
  return (unsigned short)(b >> 16);
}

__device__ __forceinline__ void gload16(const void* g, void* l) {
  __builtin_amdgcn_global_load_lds(
      (const __attribute__((address_space(1))) uint32_t*)g,
      (__attribute__((address_space(3))) uint32_t*)l, 16, 0, 0);
}

// ---------------- K1: L2-normalize rows, emit bf16 ----------------
__global__ __launch_bounds__(256) void k_normalize(const float* __restrict__ zis,
                                                   const float* __restrict__ zjs,
                                                   unsigned short* __restrict__ Abf,
                                                   unsigned short* __restrict__ Bbf) {
  int r = blockIdx.x;
  const float* src;
  unsigned short* dst;
  if (r < B_) { src = zis + (size_t)r * D_; dst = Abf + (size_t)r * D_; }
  else        { src = zjs + (size_t)(r - B_) * D_; dst = Bbf + (size_t)(r - B_) * D_; }
  int t = threadIdx.x;
  float4 v = reinterpret_cast<const float4*>(src)[t];
  float ss = v.x*v.x + v.y*v.y + v.z*v.z + v.w*v.w;
  #pragma unroll
  for (int o = 32; o >= 1; o >>= 1) ss += __shfl_down(ss, o);
  __shared__ float red[4];
  if ((t & 63) == 0) red[t >> 6] = ss;
  __syncthreads();
  float sc = rsqrtf(red[0] + red[1] + red[2] + red[3]);
  ushort4 o4;
  o4.x = f2bf(v.x * sc); o4.y = f2bf(v.y * sc);
  o4.z = f2bf(v.z * sc); o4.w = f2bf(v.w * sc);
  reinterpret_cast<ushort4*>(dst)[t] = o4;
}

// ---------------- K2: GEMM with fully fused statistics epilogue ----------------
// No C store. Per tile: row/col partials of {max, E=sum exp2(x*KE), E2=sum e*x},
// plus diag extraction on bx==by blocks.
__global__ __launch_bounds__(256) void k_gemm(const unsigned short* __restrict__ A,
                                              const unsigned short* __restrict__ B,
                                              float* __restrict__ rmax_p,
                                              float* __restrict__ rE_p,
                                              float* __restrict__ rE2_p,
                                              float* __restrict__ cmax_p,
                                              float* __restrict__ cE_p,
                                              float* __restrict__ cE2_p,
                                              float* __restrict__ diag) {
  __shared__ unsigned short As[128 * 32];
  __shared__ unsigned short Bs[128 * 32];
  __shared__ float rP[2][128][3];   // [wc][row][{max,E,E2}]
  __shared__ float cP[2][128][3];   // [wr][col][{max,E,E2}]
  const int tid = threadIdx.x;
  const int wid = tid >> 6;
  const int lane = tid & 63;
  const int wr = wid >> 1, wc = wid & 1;
  const int by = blockIdx.y, bx = blockIdx.x;

  f32x4 acc[4][4] = {};

  const int lrow = lane >> 2;        // 0..15 within chunk
  const int lcol = (lane & 3) * 8;   // k offset (elements)
  const int frow = lane & 15;
  const int fcol = (lane >> 4) * 8;

  for (int k0 = 0; k0 < D_; k0 += 32) {
    #pragma unroll
    for (int i = 0; i < 2; ++i) {
      int chunk = i * 4 + wid;       // 0..7 ; 1KB (16 rows) each
      int r = chunk * 16 + lrow;     // 0..127
      gload16(A + (size_t)(by * 128 + r) * D_ + k0 + lcol, &As[chunk * 512]);
      gload16(B + (size_t)(bx * 128 + r) * D_ + k0 + lcol, &Bs[chunk * 512]);
    }
    __syncthreads();
    bf16x8 af[4], bfr[4];
    #pragma unroll
    for (int m = 0; m < 4; ++m)
      af[m] = *reinterpret_cast<const bf16x8*>(&As[(wr*64 + m*16 + frow) * 32 + fcol]);
    #pragma unroll
    for (int n = 0; n < 4; ++n)
      bfr[n] = *reinterpret_cast<const bf16x8*>(&Bs[(wc*64 + n*16 + frow) * 32 + fcol]);
    #pragma unroll
    for (int m = 0; m < 4; ++m)
      #pragma unroll
      for (int n = 0; n < 4; ++n)
        acc[m][n] = __builtin_amdgcn_mfma_f32_16x16x32_bf16(af[m], bfr[n], acc[m][n], 0, 0, 0);
    __syncthreads();
  }

  // --- diag extraction (C/D layout: row=(lane>>4)*4+q, col=lane&15) ---
  if (bx == by && wr == wc) {
    #pragma unroll
    for (int m = 0; m < 4; ++m)
      #pragma unroll
      for (int q = 0; q < 4; ++q)
        if ((lane & 15) == ((lane >> 4) * 4 + q))
          diag[by * 128 + wr * 64 + m * 16 + (lane & 15)] = acc[m][m][q];
  }

  // --- row partials: per (m,q), reduce over n and lane&15 ---
  #pragma unroll
  for (int m = 0; m < 4; ++m)
    #pragma unroll
    for (int q = 0; q < 4; ++q) {
      float smax = -3.4e38f, sE = 0.f, sE2 = 0.f;
      #pragma unroll
      for (int n = 0; n < 4; ++n) {
        float x = acc[m][n][q];
        float e = exp2f(x * KE);
        smax = fmaxf(smax, x);
        sE += e;
        sE2 += e * x;
      }
      #pragma unroll
      for (int o = 1; o <= 8; o <<= 1) {
        smax = fmaxf(smax, __shfl_xor(smax, o));
        sE  += __shfl_xor(sE, o);
        sE2 += __shfl_xor(sE2, o);
      }
      if ((lane & 15) == 0) {
        int r = wr * 64 + m * 16 + (lane >> 4) * 4 + q;
        rP[wc][r][0] = smax; rP[wc][r][1] = sE; rP[wc][r][2] = sE2;
      }
    }

  // --- col partials: per n, reduce over (m,q) locally then lane>>4 ---
  #pragma unroll
  for (int n = 0; n < 4; ++n) {
    float smax = -3.4e38f, sE = 0.f, sE2 = 0.f;
    #pragma unroll
    for (int m = 0; m < 4; ++m)
      #pragma unroll
      for (int q = 0; q < 4; ++q) {
        float x = acc[m][n][q];
        float e = exp2f(x * KE);
        smax = fmaxf(smax, x);
        sE += e;
        sE2 += e * x;
      }
    #pragma unroll
    for (int o = 16; o <= 32; o <<= 1) {
      smax = fmaxf(smax, __shfl_xor(smax, o));
      sE  += __shfl_xor(sE, o);
      sE2 += __shfl_xor(sE2, o);
    }
    if (lane < 16) {
      int c = wc * 64 + n * 16 + lane;
      cP[wr][c][0] = smax; cP[wr][c][1] = sE; cP[wr][c][2] = sE2;
    }
  }
  __syncthreads();

  if (tid < 128) {
    int i = tid;
    size_t o = (size_t)bx * B_ + by * 128 + i;
    rmax_p[o] = fmaxf(rP[0][i][0], rP[1][i][0]);
    rE_p[o]   = rP[0][i][1] + rP[1][i][1];
    rE2_p[o]  = rP[0][i][2] + rP[1][i][2];
  } else {
    int c = tid - 128;
    size_t o = (size_t)by * B_ + bx * 128 + c;
    cmax_p[o] = fmaxf(cP[0][c][0], cP[1][c][0]);
    cE_p[o]   = cP[0][c][1] + cP[1][c][1];
    cE2_p[o]  = cP[0][c][2] + cP[1][c][2];
  }
}

// ---------------- K3: reduce partials -> per-index losses -> block partial sums ----
__global__ __launch_bounds__(256) void k_reduce(
    const float* __restrict__ rmax_p, const float* __restrict__ rE_p,
    const float* __restrict__ rE2_p,  const float* __restrict__ cmax_p,
    const float* __restrict__ cE_p,   const float* __restrict__ cE2_p,
    const float* __restrict__ diag,
    const float* __restrict__ bI, const float* __restrict__ bT,
    const float* __restrict__ sI, const float* __restrict__ sT,
    const int* __restrict__ ids, float* __restrict__ partial) {
  const int t = threadIdx.x;
  const int i = blockIdx.x * 256 + t;
  const float dg = diag[i];
  const int id = ids[i];
  const float ed = exp2f(dg * KE);

  // image (row) side
  float mx = -3.4e38f, E = 0.f, E2 = 0.f;
  for (int p = 0; p < 32; ++p) {
    size_t o = (size_t)p * B_ + i;
    mx = fmaxf(mx, rmax_p[o]); E += rE_p[o]; E2 += rE2_p[o];
  }
  float oldb = bI[id];
  float newb = fmaxf((mx - dg) * TINV, oldb);
  float sc = exp2f(-(dg * TINV + newb) * LOG2E);
  float S1 = (E - ed) * sc;
  float S2 = (E2 - dg * E) * sc;
  float g = S1 * INV_BM1;
  float sn = 0.2f * sI[id] * exp2f((oldb - newb) * LOG2E) + 0.8f * g;
  float li = S2 / fmaxf(sn, 1e-14f) * INV_BM1;

  // text (col) side
  mx = -3.4e38f; E = 0.f; E2 = 0.f;
  for (int p = 0; p < 32; ++p) {
    size_t o = (size_t)p * B_ + i;
    mx = fmaxf(mx, cmax_p[o]); E += cE_p[o]; E2 += cE2_p[o];
  }
  oldb = bT[id];
  newb = fmaxf((mx - dg) * TINV, oldb);
  sc = exp2f(-(dg * TINV + newb) * LOG2E);
  S1 = (E - ed) * sc;
  S2 = (E2 - dg * E) * sc;
  g = S1 * INV_BM1;
  sn = 0.2f * sT[id] * exp2f((oldb - newb) * LOG2E) + 0.8f * g;
  float lt = S2 / fmaxf(sn, 1e-14f) * INV_BM1;

  float v = (0.5f * li + 0.5f * lt) * (1.0f / (float)B_);
  #pragma unroll
  for (int o = 32; o >= 1; o >>= 1) v += __shfl_down(v, o);
  __shared__ float red[4];
  if ((t & 63) == 0) red[t >> 6] = v;
  __syncthreads();
  if (t == 0) partial[blockIdx.x] = red[0] + red[1] + red[2] + red[3];
}

__global__ void k_final2(const float* __restrict__ partial, float* __restrict__ out) {
  float v = (threadIdx.x < 16) ? partial[threadIdx.x] : 0.f;
  #pragma unroll
  for (int o = 32; o >= 1; o >>= 1) v += __shfl_down(v, o);
  if (threadIdx.x == 0) out[0] = v;
}

extern "C" void kernel_launch(void* const* d_in, const int* in_sizes, int n_in,
                              void* d_out, int out_size, void* d_ws, size_t ws_size,
                              hipStream_t stream) {
  const float* zis = (const float*)d_in[0];
  const float* zjs = (const float*)d_in[1];
  const float* s_I = (const float*)d_in[2];
  const float* s_T = (const float*)d_in[3];
  const float* b_I = (const float*)d_in[4];
  const float* b_T = (const float*)d_in[5];
  const int*   ids = (const int*)d_in[6];

  char* ws = (char*)d_ws;
  size_t off = 0;
  auto alloc = [&](size_t bytes) -> void* {
    void* p = ws + off;
    off = (off + bytes + 255) & ~(size_t)255;
    return p;
  };
  unsigned short* Abf = (unsigned short*)alloc((size_t)B_ * D_ * 2);   // 8 MB
  unsigned short* Bbf = (unsigned short*)alloc((size_t)B_ * D_ * 2);   // 8 MB
  float* rmax_p = (float*)alloc((size_t)32 * B_ * 4);                  // 512 KB each
  float* rE_p   = (float*)alloc((size_t)32 * B_ * 4);
  float* rE2_p  = (float*)alloc((size_t)32 * B_ * 4);
  float* cmax_p = (float*)alloc((size_t)32 * B_ * 4);
  float* cE_p   = (float*)alloc((size_t)32 * B_ * 4);
  float* cE2_p  = (float*)alloc((size_t)32 * B_ * 4);
  float* diag   = (float*)alloc(B_ * 4);
  float* partial = (float*)alloc(16 * 4);

  k_normalize<<<2 * B_, 256, 0, stream>>>(zis, zjs, Abf, Bbf);
  k_gemm<<<dim3(32, 32), 256, 0, stream>>>(Abf, Bbf, rmax_p, rE_p, rE2_p,
                                           cmax_p, cE_p, cE2_p, diag);
  k_reduce<<<16, 256, 0, stream>>>(rmax_p, rE_p, rE2_p, cmax_p, cE_p, cE2_p,
                                   diag, b_I, b_T, s_I, s_T, ids, partial);
  k_final2<<<1, 64, 0, stream>>>(partial, (float*)d_out);
}